// Round 1
// baseline (125.262 us; speedup 1.0000x reference)
//
#include <hip/hip_runtime.h>
#include <hip/hip_bf16.h>

// out[b,d,r] = sum_c p[b,c] * softmax_d( x[b,:] @ W[:, c*8+d, r] + bias[c,d,r] )
// B=16384, F=128, C=8, R=64.  bf16 MFMA 16x16x32, fully fused.
//
// R10->R11: the R10 shell was LDS-read-BW bound (~2.5x MFMA floor): each
// B-fragment ds_read_b128 fed exactly ONE MFMA (M=16 rows/wave, n-tile =
// 16 r's for one d).  Fix: M=32 rows/wave (2 m-tiles share every B-read ->
// 32 FLOP/B) made register-feasible by repacking the n-tile as
// [2 d-values x 8 r] so 4 accs (16 regs) cover all 8 d per m-tile.
// Softmax d-sum = in-lane tree over 4 accs + one shfl_xor(8) pairing the
// d-LSB halves of each 16-lane group.  acc 32 + O 32 + afr 32 ~ 125 regs
// -> launch_bounds(256,3) (no spills, 12 waves/CU, 3 blocks/CU).
// Stage per c drops 32KB->16KB/block; wf L2 traffic halves.

#define B_ROWS   16384
#define F_DIM    128
#define NCOL     4096      // C*C*R
#define OUT_STRIDE 512     // C*R
#define LOG2E    1.44269504088896340736f

typedef __bf16 bf16x8 __attribute__((ext_vector_type(8)));
typedef float  f32x4  __attribute__((ext_vector_type(4)));

#define AS1(p) ((const __attribute__((address_space(1))) unsigned int*)(p))
#define AS3(p) ((__attribute__((address_space(3))) unsigned int*)(p))

// ---------------------------------------------------------------------------
// Prepass: W fp32 (128 x 4096 row-major) -> bf16 MFMA B-fragments.
// Fragment gf = ((c*4 + t)*8 + w)*4 + kk covers the 16 columns
//   n(l15) = c*512 + (2t + (l15>>3))*64 + w*8 + (l15&7)
// (i.e. the [d = 2t + h] pair for r-chunk w), with
//   k = kk*32 + (lane>>4)*8 + j   held in element j of the lane's bf16x8.
// ---------------------------------------------------------------------------
__global__ void wconv_kernel(const float* __restrict__ W, __bf16* __restrict__ wf) {
    int f    = blockIdx.x * 256 + threadIdx.x;  // 0..65535
    int lane = f & 63;
    int gf   = f >> 6;          // fragment id 0..1023
    int kk   = gf & 3;
    int w    = (gf >> 2) & 7;
    int t    = (gf >> 5) & 3;
    int c    = gf >> 7;
    int l15  = lane & 15;
    int kbase = kk * 32 + (lane >> 4) * 8;
    int col   = c * 512 + (2 * t + (l15 >> 3)) * 64 + w * 8 + (l15 & 7);
    bf16x8 frag;
#pragma unroll
    for (int j = 0; j < 8; ++j)
        frag[j] = (__bf16)W[(kbase + j) * NCOL + col];
    *(bf16x8*)(wf + (size_t)f * 8) = frag;
}

// ---------------------------------------------------------------------------
// Fused GEMM + bias + softmax(d) + p-contraction.
// Block: 256 thr (4 waves), 128 batch rows, one r8-chunk w = blockIdx&7.
// Wave ww owns rows b0..b0+32 (2 m-tiles).  Per c: 16 fragments (4 t x 4 kk)
// staged to LDS (wave ww stages t=ww); each ds_read_b128 feeds 2 MFMAs.
// acc[m][t] covers d = 2t + h (h = lane bit 3) for 8 r's.
// Softmax over d: in-lane sum over t + shfl_xor(8) to merge the h halves.
// C/D layout: col=lane&15 -> (h,q), row=quad*4+jj -> batch row.
// ---------------------------------------------------------------------------
__global__ __launch_bounds__(256, 3)
void fused_kernel(const float* __restrict__ x, const float* __restrict__ p,
                  const float* __restrict__ bias, const __bf16* __restrict__ wf,
                  float* __restrict__ out) {
    __shared__ __align__(16) char lds[16384];   // 16 fragments (4 t x 4 kk)

    const int lane = threadIdx.x & 63;
    const int ww   = threadIdx.x >> 6;   // wave 0..3
    const int quad = lane >> 4;
    const int l15  = lane & 15;
    const int h    = l15 >> 3;           // d LSB
    const int q    = l15 & 7;            // r within chunk
    const int w    = blockIdx.x & 7;     // r8-chunk
    const int b0   = (blockIdx.x >> 3) * 128 + ww * 32;

    // A fragments: afr[m][kk][j] = x_bf16[b0+m*16+l15][kk*32 + quad*8 + j]
    bf16x8 afr[2][4];
#pragma unroll
    for (int m = 0; m < 2; ++m) {
        const float* xr = x + (size_t)(b0 + m * 16 + l15) * F_DIM + quad * 8;
#pragma unroll
        for (int kk = 0; kk < 4; ++kk) {
            float4 lo = *(const float4*)(xr + kk * 32);
            float4 hi = *(const float4*)(xr + kk * 32 + 4);
            bf16x8 f;
            f[0] = (__bf16)lo.x; f[1] = (__bf16)lo.y;
            f[2] = (__bf16)lo.z; f[3] = (__bf16)lo.w;
            f[4] = (__bf16)hi.x; f[5] = (__bf16)hi.y;
            f[6] = (__bf16)hi.z; f[7] = (__bf16)hi.w;
            afr[m][kk] = f;
        }
    }

    float O[2][4][4] = {};   // [m][t][jj] output accumulator over c

#pragma unroll 1
    for (int c = 0; c < 8; ++c) {
        // ---- stage c's 16 fragments: wave ww takes t = ww ------------------
        {
            const __bf16* src = wf + (size_t)(((c * 4 + ww) * 8 + w) * 4) * 512;
#pragma unroll
            for (int kk = 0; kk < 4; ++kk)
                __builtin_amdgcn_global_load_lds(
                    AS1(src + kk * 512 + lane * 8),
                    AS3(lds + (ww * 4 + kk) * 1024), 16, 0, 0);
        }
        __syncthreads();

        float bvl[4];
#pragma unroll
        for (int t = 0; t < 4; ++t)
            bvl[t] = bias[c * 512 + (2 * t + h) * 64 + w * 8 + q] * LOG2E;

        f32x4 acc[2][4] = {};
#pragma unroll
        for (int kk = 0; kk < 4; ++kk)
#pragma unroll
            for (int t = 0; t < 4; ++t) {
                bf16x8 bfr = *(const bf16x8*)(lds + (t * 4 + kk) * 1024 + lane * 16);
                acc[0][t] = __builtin_amdgcn_mfma_f32_16x16x32_bf16(
                                afr[0][kk], bfr, acc[0][t], 0, 0, 0);
                acc[1][t] = __builtin_amdgcn_mfma_f32_16x16x32_bf16(
                                afr[1][kk], bfr, acc[1][t], 0, 0, 0);
            }

#pragma unroll
        for (int m = 0; m < 2; ++m) {
#pragma unroll
            for (int jj = 0; jj < 4; ++jj) {
                float pv = p[(size_t)(b0 + m * 16 + quad * 4 + jj) * 8 + c];
                float e0 = __builtin_amdgcn_exp2f(
                               __builtin_fmaf(acc[m][0][jj], LOG2E, bvl[0]));
                float e1 = __builtin_amdgcn_exp2f(
                               __builtin_fmaf(acc[m][1][jj], LOG2E, bvl[1]));
                float e2 = __builtin_amdgcn_exp2f(
                               __builtin_fmaf(acc[m][2][jj], LOG2E, bvl[2]));
                float e3 = __builtin_amdgcn_exp2f(
                               __builtin_fmaf(acc[m][3][jj], LOG2E, bvl[3]));
                float s4 = (e0 + e1) + (e2 + e3);      // this lane's 4 d's
                float s8 = s4 + __shfl_xor(s4, 8, 64); // + other-h 4 d's
                float scale = pv * __builtin_amdgcn_rcpf(s8);
                O[m][0][jj] = __builtin_fmaf(e0, scale, O[m][0][jj]);
                O[m][1][jj] = __builtin_fmaf(e1, scale, O[m][1][jj]);
                O[m][2][jj] = __builtin_fmaf(e2, scale, O[m][2][jj]);
                O[m][3][jj] = __builtin_fmaf(e3, scale, O[m][3][jj]);
            }
        }
        __syncthreads();   // protect LDS before next c's staging
    }

    // ---- stores: out[b, (2t+h)*64 + w*8 + q] — 32B segments per quad ------
#pragma unroll
    for (int m = 0; m < 2; ++m)
#pragma unroll
        for (int jj = 0; jj < 4; ++jj) {
            float* orow = out + (size_t)(b0 + m * 16 + quad * 4 + jj) * OUT_STRIDE
                          + h * 64 + w * 8 + q;
#pragma unroll
            for (int t = 0; t < 4; ++t)
                orow[t * 128] = O[m][t][jj];
        }
}

extern "C" void kernel_launch(void* const* d_in, const int* in_sizes, int n_in,
                              void* d_out, int out_size, void* d_ws, size_t ws_size,
                              hipStream_t stream) {
    const float* x    = (const float*)d_in[0];   // (16384, 128)
    const float* p    = (const float*)d_in[1];   // (16384, 8)
    const float* W    = (const float*)d_in[2];   // (128, 64, 64)
    const float* bias = (const float*)d_in[3];   // (8, 8, 64)
    float* out = (float*)d_out;                  // (16384, 8, 64)
    __bf16* wf = (__bf16*)d_ws;                  // 1 MB bf16 fragments

    wconv_kernel<<<dim3(256), dim3(256), 0, stream>>>(W, wf);
    fused_kernel<<<dim3(1024), dim3(256), 0, stream>>>(x, p, bias, wf, out);
}

// Round 2
// 112.134 us; speedup vs baseline: 1.1171x; 1.1171x over previous
//
#include <hip/hip_runtime.h>
#include <hip/hip_bf16.h>

// out[b,d,r] = sum_c p[b,c] * softmax_d( x[b,:] @ W[:, c*8+d, r] + bias[c,d,r] )
// B=16384, F=128, C=8, R=64.  bf16 MFMA 16x16x32, fully fused.
//
// R11->R12: R11's m=2 B-reuse was right but regressed 4x: >128 total regs
// (launch_bounds(256,3)) dropped residency to ~2-3 blocks/CU while the grid
// needs exactly 4/CU -> serialized extra pass + single-buffered stage latency
// fully exposed (MfmaUtil 10%, VALU 21%, Occ 23% = all-stall).  Fixes:
//  - launch_bounds(256,4): hard 128-reg cap -> 4 blocks/CU guaranteed.
//  - double-buffered LDS (2x16KB), stage(c+1) issued right after the ONE
//    barrier per c; the barrier's implicit vmcnt(0) drains loads that had a
//    full compute phase to land (T3-style, compiler-friendly).
//  - w-major grid (w = blockIdx>>7): all 8 r-chunks of a row-group on one
//    XCD -> x L2-filled once per XCD (was 8x), out 64B-line halves same-XCD.
//  - bias folded into MFMA C-in (replaces zero-init, saves 32 fma/c/wave);
//    pvv hoisted above MFMA loop so p latency hides under MFMAs.

#define B_ROWS   16384
#define F_DIM    128
#define NCOL     4096      // C*C*R
#define OUT_STRIDE 512     // C*R
#define LOG2E    1.44269504088896340736f

typedef __bf16 bf16x8 __attribute__((ext_vector_type(8)));
typedef float  f32x4  __attribute__((ext_vector_type(4)));

#define AS1(p) ((const __attribute__((address_space(1))) unsigned int*)(p))
#define AS3(p) ((__attribute__((address_space(3))) unsigned int*)(p))

// ---------------------------------------------------------------------------
// Prepass: W fp32 (128 x 4096 row-major) -> bf16 MFMA B-fragments.
// Fragment gf = ((c*4 + t)*8 + w)*4 + kk covers the 16 columns
//   n(l15) = c*512 + (2t + (l15>>3))*64 + w*8 + (l15&7)
// with k = kk*32 + (lane>>4)*8 + j in element j of the lane's bf16x8.
// ---------------------------------------------------------------------------
__global__ void wconv_kernel(const float* __restrict__ W, __bf16* __restrict__ wf) {
    int f    = blockIdx.x * 256 + threadIdx.x;  // 0..65535
    int lane = f & 63;
    int gf   = f >> 6;          // fragment id 0..1023
    int kk   = gf & 3;
    int w    = (gf >> 2) & 7;
    int t    = (gf >> 5) & 3;
    int c    = gf >> 7;
    int l15  = lane & 15;
    int kbase = kk * 32 + (lane >> 4) * 8;
    int col   = c * 512 + (2 * t + (l15 >> 3)) * 64 + w * 8 + (l15 & 7);
    bf16x8 frag;
#pragma unroll
    for (int j = 0; j < 8; ++j)
        frag[j] = (__bf16)W[(kbase + j) * NCOL + col];
    *(bf16x8*)(wf + (size_t)f * 8) = frag;
}

// ---------------------------------------------------------------------------
// Fused GEMM + bias + softmax(d) + p-contraction.
// Block: 256 thr (4 waves), 128 batch rows, one r8-chunk w = blockIdx>>7.
// Wave ww owns rows b0..b0+32 (2 m-tiles, so each B ds_read feeds 2 MFMAs).
// Per c: 16 fragments (4 t x 4 kk) double-buffer-staged (wave ww stages t=ww).
// acc[m][t] covers d = 2t + h (h = lane bit 3) for 8 r's; C-in = bias.
// Softmax over d: in-lane sum over t + shfl_xor(8) merging the h halves.
// ---------------------------------------------------------------------------
__global__ __launch_bounds__(256, 4)
void fused_kernel(const float* __restrict__ x, const float* __restrict__ p,
                  const float* __restrict__ bias, const __bf16* __restrict__ wf,
                  float* __restrict__ out) {
    __shared__ __align__(16) char lds[32768];   // 2 x (16 fragments = 16 KB)

    const int lane = threadIdx.x & 63;
    const int ww   = threadIdx.x >> 6;   // wave 0..3
    const int quad = lane >> 4;
    const int l15  = lane & 15;
    const int h    = l15 >> 3;           // d LSB
    const int q    = l15 & 7;            // r within chunk
    const int w    = blockIdx.x >> 7;    // r8-chunk (w-major: same-XCD per g)
    const int g    = blockIdx.x & 127;   // row-group
    const int b0   = g * 128 + ww * 32;

    // A fragments: afr[m][kk][j] = x_bf16[b0+m*16+l15][kk*32 + quad*8 + j]
    bf16x8 afr[2][4];
#pragma unroll
    for (int m = 0; m < 2; ++m) {
        const float* xr = x + (size_t)(b0 + m * 16 + l15) * F_DIM + quad * 8;
#pragma unroll
        for (int kk = 0; kk < 4; ++kk) {
            float4 lo = *(const float4*)(xr + kk * 32);
            float4 hi = *(const float4*)(xr + kk * 32 + 4);
            bf16x8 f;
            f[0] = (__bf16)lo.x; f[1] = (__bf16)lo.y;
            f[2] = (__bf16)lo.z; f[3] = (__bf16)lo.w;
            f[4] = (__bf16)hi.x; f[5] = (__bf16)hi.y;
            f[6] = (__bf16)hi.z; f[7] = (__bf16)hi.w;
            afr[m][kk] = f;
        }
    }

    float O[2][4][4] = {};   // [m][t][jj] output accumulator over c

    // ---- prologue: stage c=0 into buffer 0 --------------------------------
    {
        const __bf16* src = wf + (size_t)((ww * 8 + w) * 4) * 512;
#pragma unroll
        for (int kk = 0; kk < 4; ++kk)
            __builtin_amdgcn_global_load_lds(
                AS1(src + kk * 512 + lane * 8),
                AS3(lds + (ww * 4 + kk) * 1024), 16, 0, 0);
    }

#pragma unroll 1
    for (int c = 0; c < 8; ++c) {
        // barrier: stage(c) landed (implicit vmcnt(0), issued a full phase
        // ago) AND all waves done reading buf[(c+1)&1] from iteration c-1.
        __syncthreads();

        // ---- issue stage(c+1) into the other buffer (hidden under compute)
        if (c < 7) {
            const __bf16* src = wf + (size_t)((((c + 1) * 4 + ww) * 8 + w) * 4) * 512;
            char* dst = lds + ((c + 1) & 1) * 16384;
#pragma unroll
            for (int kk = 0; kk < 4; ++kk)
                __builtin_amdgcn_global_load_lds(
                    AS1(src + kk * 512 + lane * 8),
                    AS3(dst + (ww * 4 + kk) * 1024), 16, 0, 0);
        }

        // ---- p and bias loads issued before MFMAs (latency hides under them)
        float pvv[2][4];
#pragma unroll
        for (int m = 0; m < 2; ++m)
#pragma unroll
            for (int jj = 0; jj < 4; ++jj)
                pvv[m][jj] = p[(size_t)(b0 + m * 16 + quad * 4 + jj) * 8 + c];

        float bvl[4];
#pragma unroll
        for (int t = 0; t < 4; ++t)
            bvl[t] = bias[c * 512 + (2 * t + h) * 64 + w * 8 + q];

        // ---- MFMA: C-in = bias (row-invariant per col) --------------------
        f32x4 acc[2][4];
#pragma unroll
        for (int t = 0; t < 4; ++t) {
            f32x4 binit = {bvl[t], bvl[t], bvl[t], bvl[t]};
            acc[0][t] = binit;
            acc[1][t] = binit;
        }

        const char* buf = lds + (c & 1) * 16384;
#pragma unroll
        for (int kk = 0; kk < 4; ++kk)
#pragma unroll
            for (int t = 0; t < 4; ++t) {
                bf16x8 bfr = *(const bf16x8*)(buf + (t * 4 + kk) * 1024 + lane * 16);
                acc[0][t] = __builtin_amdgcn_mfma_f32_16x16x32_bf16(
                                afr[0][kk], bfr, acc[0][t], 0, 0, 0);
                acc[1][t] = __builtin_amdgcn_mfma_f32_16x16x32_bf16(
                                afr[1][kk], bfr, acc[1][t], 0, 0, 0);
            }

        // ---- softmax over d + p-weighted accumulate -----------------------
#pragma unroll
        for (int m = 0; m < 2; ++m) {
#pragma unroll
            for (int jj = 0; jj < 4; ++jj) {
                float e0 = __builtin_amdgcn_exp2f(acc[m][0][jj] * LOG2E);
                float e1 = __builtin_amdgcn_exp2f(acc[m][1][jj] * LOG2E);
                float e2 = __builtin_amdgcn_exp2f(acc[m][2][jj] * LOG2E);
                float e3 = __builtin_amdgcn_exp2f(acc[m][3][jj] * LOG2E);
                float s4 = (e0 + e1) + (e2 + e3);      // this lane's 4 d's
                float s8 = s4 + __shfl_xor(s4, 8, 64); // + other-h 4 d's
                float scale = pvv[m][jj] * __builtin_amdgcn_rcpf(s8);
                O[m][0][jj] = __builtin_fmaf(e0, scale, O[m][0][jj]);
                O[m][1][jj] = __builtin_fmaf(e1, scale, O[m][1][jj]);
                O[m][2][jj] = __builtin_fmaf(e2, scale, O[m][2][jj]);
                O[m][3][jj] = __builtin_fmaf(e3, scale, O[m][3][jj]);
            }
        }
        // no second barrier: next iteration's __syncthreads covers the
        // write-after-read hazard on buf[(c+1)&1].
    }

    // ---- stores: out[b, (2t+h)*64 + w*8 + q] — 32B segments per quad ------
#pragma unroll
    for (int m = 0; m < 2; ++m)
#pragma unroll
        for (int jj = 0; jj < 4; ++jj) {
            float* orow = out + (size_t)(b0 + m * 16 + quad * 4 + jj) * OUT_STRIDE
                          + h * 64 + w * 8 + q;
#pragma unroll
            for (int t = 0; t < 4; ++t)
                orow[t * 128] = O[m][t][jj];
        }
}

extern "C" void kernel_launch(void* const* d_in, const int* in_sizes, int n_in,
                              void* d_out, int out_size, void* d_ws, size_t ws_size,
                              hipStream_t stream) {
    const float* x    = (const float*)d_in[0];   // (16384, 128)
    const float* p    = (const float*)d_in[1];   // (16384, 8)
    const float* W    = (const float*)d_in[2];   // (128, 64, 64)
    const float* bias = (const float*)d_in[3];   // (8, 8, 64)
    float* out = (float*)d_out;                  // (16384, 8, 64)
    __bf16* wf = (__bf16*)d_ws;                  // 1 MB bf16 fragments

    wconv_kernel<<<dim3(256), dim3(256), 0, stream>>>(W, wf);
    fused_kernel<<<dim3(1024), dim3(256), 0, stream>>>(x, p, bias, wf, out);
}